// Round 4
// baseline (819.661 us; speedup 1.0000x reference)
//
#include <hip/hip_runtime.h>
#include <hip/hip_cooperative_groups.h>
#include <stdint.h>

namespace cg = cooperative_groups;

#define B_N      16384
#define NREG     64
#define KNB      5
#define SAMPLE   2048
#define NSUB     16
#define SUBLEN   (SAMPLE / NSUB)             // 128
#define NCHUNK   16
#define CHUNKLEN ((B_N - SAMPLE) / NCHUNK)   // 896
#define NBLOCKS  1024
#define SLOTS    (KNB + NSUB * KNB)          // 85 (seed 5 + 16*5; scan reuses the 80)
#define SENT     0xFFFF

static __device__ __forceinline__ float inf32() { return __int_as_float(0x7f800000); }

// flat 5-slot sorted-insert (ascending), tracking indices
#define INS5(nv, jj)                                                        \
    {                                                                       \
        bool c4 = (nv) < s4, c3 = (nv) < s3, c2 = (nv) < s2,                \
             c1 = (nv) < s1, c0 = (nv) < s0;                                \
        s4 = c3 ? s3 : (c4 ? (nv) : s4);  i4 = c3 ? i3 : (c4 ? (jj) : i4);  \
        s3 = c2 ? s2 : (c3 ? (nv) : s3);  i3 = c2 ? i2 : (c3 ? (jj) : i3);  \
        s2 = c1 ? s1 : (c2 ? (nv) : s2);  i2 = c1 ? i1 : (c2 ? (jj) : i2);  \
        s1 = c0 ? s0 : (c1 ? (nv) : s1);  i1 = c0 ? i0 : (c1 ? (jj) : i1);  \
        s0 = c0 ? (nv) : s0;              i0 = c0 ? (jj) : i0;              \
    }

__global__ __launch_bounds__(256, 4) void mega_kernel(
    const float* __restrict__ c, const float* __restrict__ x,
    const int* __restrict__ ids, float* __restrict__ out,
    float4* __restrict__ pre, float* __restrict__ tau,
    float* __restrict__ wsreg, float* __restrict__ spart,
    unsigned short* __restrict__ cand) {
    cg::grid_group grid = cg::this_grid();
    const int blk = blockIdx.x;
    const int tid = threadIdx.x;
    __shared__ float sb[4][7];

    // ================= P0: pre (blocks 0..63) || region (blocks 64..127) ======
    if (blk < 64) {
        int j = blk * 256 + tid;
        float jx = x[3 * j + 0], jy = x[3 * j + 1], jz = x[3 * j + 2];
        pre[j] = make_float4(-2.f * jx, -2.f * jy, -2.f * jz,
                             jx * jx + jy * jy + jz * jz);
    } else if (blk < 128) {
        const int r = blk - 64;
        float cnt = 0.f, sx = 0.f, sy = 0.f, sz = 0.f, sxx = 0.f, syy = 0.f, szz = 0.f;
        for (int i = tid; i < B_N; i += 256) {
            int id = ids[i];
            float m = (id == r) ? 1.0f : 0.0f;
            float px = c[3 * i + 0], py = c[3 * i + 1], pz = c[3 * i + 2];
            cnt += m;
            sx += m * px;  sy += m * py;  sz += m * pz;
            sxx += m * px * px;  syy += m * py * py;  szz += m * pz * pz;
        }
        for (int off = 32; off > 0; off >>= 1) {
            cnt += __shfl_down(cnt, off);
            sx  += __shfl_down(sx, off);
            sy  += __shfl_down(sy, off);
            sz  += __shfl_down(sz, off);
            sxx += __shfl_down(sxx, off);
            syy += __shfl_down(syy, off);
            szz += __shfl_down(szz, off);
        }
        const int lane = tid & 63, w = tid >> 6;
        if (lane == 0) {
            sb[w][0] = cnt; sb[w][1] = sx; sb[w][2] = sy; sb[w][3] = sz;
            sb[w][4] = sxx; sb[w][5] = syy; sb[w][6] = szz;
        }
        __syncthreads();
        if (tid == 0) {
            float C = 0, SX = 0, SY = 0, SZ = 0, SXX = 0, SYY = 0, SZZ = 0;
            for (int i = 0; i < 4; i++) {
                C += sb[i][0]; SX += sb[i][1]; SY += sb[i][2]; SZ += sb[i][3];
                SXX += sb[i][4]; SYY += sb[i][5]; SZZ += sb[i][6];
            }
            float safe = fmaxf(C, 1.0f);
            float mx = SX / safe, my = SY / safe, mz = SZ / safe;
            float ssc = (SXX - C * mx * mx) + (SYY - C * my * my) + (SZZ - C * mz * mz);
            float npairs = C * (C - 1.0f) * 0.5f;
            float denom = fmaxf(npairs, 1.0f) * 3.0f;
            wsreg[r] = (C > 1.0f) ? (2.0f * ssc / denom) : 0.0f;
        }
    }
    grid.sync();

    // ================= P1: sample scan, top-5 per (q, sub) ====================
    {
        const int qb = blk & (NBLOCKS / NSUB - 1);   // 0..63
        const int sub = blk >> 6;                    // 0..15
        const int q = qb * 256 + tid;
        const float qx = x[3 * q + 0], qy = x[3 * q + 1], qz = x[3 * q + 2];

        float s0 = inf32(), s1 = inf32(), s2 = inf32(), s3 = inf32(), s4 = inf32();
        int i0 = 0, i1 = 0, i2 = 0, i3 = 0, i4 = 0;

        const int j0 = sub * SUBLEN;
        for (int jb = j0; jb < j0 + SUBLEN; jb += 8) {
            float dt[8];
#pragma unroll
            for (int u = 0; u < 8; ++u) {
                float4 pj = pre[jb + u];             // wave-uniform -> scalar loads
                dt[u] = fmaf(pj.x, qx, fmaf(pj.y, qy, fmaf(pj.z, qz, pj.w)));
            }
#pragma unroll
            for (int u = 0; u < 8; ++u) {
                int j = jb + u;
                float nv = (j != q) ? dt[u] : inf32();
                INS5(nv, j);
            }
        }
        unsigned short* w = cand + (size_t)q * SLOTS + KNB + sub * KNB;
        w[0] = (unsigned short)i0; w[1] = (unsigned short)i1; w[2] = (unsigned short)i2;
        w[3] = (unsigned short)i3; w[4] = (unsigned short)i4;
    }
    grid.sync();

    // ================= P2: tau merge (16 q per block) =========================
    if (tid < 16) {
        const int q = blk * 16 + tid;
        const float qx = x[3 * q + 0], qy = x[3 * q + 1], qz = x[3 * q + 2];
        float s0 = inf32(), s1 = inf32(), s2 = inf32(), s3 = inf32(), s4 = inf32();
        int i0 = 0, i1 = 0, i2 = 0, i3 = 0, i4 = 0;
        const unsigned short* t = cand + (size_t)q * SLOTS + KNB;
#pragma unroll 8
        for (int n = 0; n < NSUB * KNB; ++n) {
            int cd = (int)t[n];
            float4 pj = pre[cd];
            float nv = fmaf(pj.x, qx, fmaf(pj.y, qy, fmaf(pj.z, qz, pj.w)));
            INS5(nv, cd);
        }
        // bump tau by 1 ulp toward +inf so the filter admits d == tau ties
        int b = __float_as_int(s4);
        b += (b >= 0) ? 1 : -1;
        tau[q] = __int_as_float(b);
        unsigned short* w = cand + (size_t)q * SLOTS;
        w[0] = (unsigned short)i0; w[1] = (unsigned short)i1; w[2] = (unsigned short)i2;
        w[3] = (unsigned short)i3; w[4] = (unsigned short)i4;
    }
    grid.sync();

    // ================= P3: filtered scan of remaining points ==================
    {
        const int qb = blk & (NBLOCKS / NCHUNK - 1); // 0..63
        const int chunk = blk >> 6;                  // 0..15
        const int q = qb * 256 + tid;
        const float qx = x[3 * q + 0], qy = x[3 * q + 1], qz = x[3 * q + 2];

        const float t = tau[q];
        float s0 = t, s1 = t, s2 = t, s3 = t, s4 = t;
        int i0 = SENT, i1 = SENT, i2 = SENT, i3 = SENT, i4 = SENT;

        const int jbase = SAMPLE + chunk * CHUNKLEN;
        for (int jb = jbase; jb < jbase + CHUNKLEN; jb += 8) {
            float dt[8];
#pragma unroll
            for (int u = 0; u < 8; ++u) {
                float4 pj = pre[jb + u];             // wave-uniform -> scalar loads
                dt[u] = fmaf(pj.x, qx, fmaf(pj.y, qy, fmaf(pj.z, qz, pj.w)));
            }
#pragma unroll
            for (int u = 0; u < 8; ++u) {
                if (__any(dt[u] < s4)) {             // rare correlated branch
                    int j = jb + u;
                    bool p = (dt[u] < s4) && (j != q);
                    float nv = p ? dt[u] : inf32();
                    INS5(nv, j);
                }
            }
        }
        unsigned short* w = cand + (size_t)q * SLOTS + KNB + chunk * KNB;
        w[0] = (unsigned short)i0; w[1] = (unsigned short)i1; w[2] = (unsigned short)i2;
        w[3] = (unsigned short)i3; w[4] = (unsigned short)i4;
    }
    grid.sync();

    // ================= P4: final merge + c-loss (16 q per block) ==============
    float acc = 0.f;
    if (tid < 16) {
        const int q = blk * 16 + tid;
        const float qx = x[3 * q + 0], qy = x[3 * q + 1], qz = x[3 * q + 2];
        float s0 = inf32(), s1 = inf32(), s2 = inf32(), s3 = inf32(), s4 = inf32();
        int i0 = 0, i1 = 0, i2 = 0, i3 = 0, i4 = 0;
        const unsigned short* t = cand + (size_t)q * SLOTS;
#pragma unroll 5
        for (int n = 0; n < SLOTS; ++n) {
            int cd = (int)t[n];
            int safe = cd & 0x3FFF;                  // SENT -> valid addr, masked by inf
            float4 pj = pre[safe];
            float d = fmaf(pj.x, qx, fmaf(pj.y, qy, fmaf(pj.z, qz, pj.w)));
            float nv = (cd != SENT) ? d : inf32();
            INS5(nv, safe);
        }
        const float cx = c[3 * q + 0], cy = c[3 * q + 1], cz = c[3 * q + 2];
        int ks[5] = {i0, i1, i2, i3, i4};
#pragma unroll
        for (int n = 0; n < KNB; ++n) {
            int nb = ks[n];
            float dx = cx - c[3 * nb + 0];
            float dy = cy - c[3 * nb + 1];
            float dz = cz - c[3 * nb + 2];
            acc += dx * dx + dy * dy + dz * dz;
        }
    }
    // wave-0 holds all active lanes (0..15); reduce and store one partial/block
    for (int off = 32; off > 0; off >>= 1) acc += __shfl_down(acc, off);
    if (tid == 0) spart[blk] = acc;
    grid.sync();

    // ================= P5: finalize (block 0) =================================
    if (blk == 0) {
        float s = 0.f;
        for (int i = tid; i < NBLOCKS; i += 256) s += spart[i];
        float r = (tid < NREG) ? wsreg[tid] : 0.f;
        for (int off = 32; off > 0; off >>= 1) {
            s += __shfl_down(s, off);
            r += __shfl_down(r, off);
        }
        __syncthreads();   // sb reuse safety
        const int lane = tid & 63, w = tid >> 6;
        if (lane == 0) { sb[w][0] = s; sb[w][1] = r; }
        __syncthreads();
        if (tid == 0) {
            float S = sb[0][0] + sb[1][0] + sb[2][0] + sb[3][0];
            float R = sb[0][1] + sb[1][1] + sb[2][1] + sb[3][1];
            float spatial_mean = S / (float)(B_N * KNB);
            out[0] = 0.02f * R + 0.0005f * (spatial_mean / 3.0f);
        }
    }
}

extern "C" void kernel_launch(void* const* d_in, const int* in_sizes, int n_in,
                              void* d_out, int out_size, void* d_ws, size_t ws_size,
                              hipStream_t stream) {
    const float* c  = (const float*)d_in[0];   // c_points   [16384,3] f32
    const float* x  = (const float*)d_in[1];   // coords_std [16384,3] f32
    const int* ids  = (const int*)d_in[2];     // region_ids [16384] i32
    float* out = (float*)d_out;

    char* ws = (char*)d_ws;
    float4* pre = (float4*)ws;                                  // 256 KiB
    float* tau  = (float*)(ws + (size_t)B_N * 16);              // 64 KiB
    float* wsreg = tau + B_N;                                   // 64 f
    float* spart = wsreg + NREG;                                // 1024 f
    unsigned short* cand = (unsigned short*)(spart + NBLOCKS);  // 16384*85*2 = 2.79 MiB

    void* args[] = {(void*)&c, (void*)&x, (void*)&ids, (void*)&out,
                    (void*)&pre, (void*)&tau, (void*)&wsreg, (void*)&spart,
                    (void*)&cand};
    hipLaunchCooperativeKernel((const void*)mega_kernel, dim3(NBLOCKS), dim3(256),
                               args, 0, stream);
}

// Round 5
// 150.300 us; speedup vs baseline: 5.4535x; 5.4535x over previous
//
#include <hip/hip_runtime.h>
#include <stdint.h>

#define B_N    16384
#define NREG   64
#define KNB    5
#define SAMPLE 2048
#define QPB    16                    // queries per block
#define TPQ    16                    // threads per query
#define SUBLEN (SAMPLE / TPQ)        // 128 sample points per thread
#define REM    (B_N - SAMPLE)        // 14336
#define CHUNK  (REM / TPQ)           // 896 scan points per thread
#define NBLK   (B_N / QPB)           // 1024 blocks
#define SENT   0xFFFF

static __device__ __forceinline__ float inf32() { return __int_as_float(0x7f800000); }

// flat 5-slot sorted-insert (ascending), strict < => ties keep earlier insert (smaller j)
#define INS5(nv, jj)                                                        \
    {                                                                       \
        bool c4 = (nv) < s4, c3 = (nv) < s3, c2 = (nv) < s2,                \
             c1 = (nv) < s1, c0 = (nv) < s0;                                \
        s4 = c3 ? s3 : (c4 ? (nv) : s4);  i4 = c3 ? i3 : (c4 ? (jj) : i4);  \
        s3 = c2 ? s2 : (c3 ? (nv) : s3);  i3 = c2 ? i2 : (c3 ? (jj) : i3);  \
        s2 = c1 ? s1 : (c2 ? (nv) : s2);  i2 = c1 ? i1 : (c2 ? (jj) : i2);  \
        s1 = c0 ? s0 : (c1 ? (nv) : s1);  i1 = c0 ? i0 : (c1 ? (jj) : i1);  \
        s0 = c0 ? (nv) : s0;              i0 = c0 ? (jj) : i0;              \
    }

// ---------------- K1: pre (blocks 0..63) + region (blocks 64..127) ----------------
__global__ __launch_bounds__(256) void prep_kernel(const float* __restrict__ c,
                                                   const float* __restrict__ x,
                                                   const int* __restrict__ ids,
                                                   float4* __restrict__ pre,
                                                   float* __restrict__ wsreg) {
    const int blk = blockIdx.x;
    const int tid = threadIdx.x;
    if (blk < 64) {
        int j = blk * 256 + tid;
        float jx = x[3 * j + 0], jy = x[3 * j + 1], jz = x[3 * j + 2];
        pre[j] = make_float4(-2.f * jx, -2.f * jy, -2.f * jz,
                             jx * jx + jy * jy + jz * jz);
        return;
    }
    const int r = blk - 64;
    float cnt = 0.f, sx = 0.f, sy = 0.f, sz = 0.f, sxx = 0.f, syy = 0.f, szz = 0.f;
    for (int i = tid; i < B_N; i += 256) {
        int id = ids[i];
        float m = (id == r) ? 1.0f : 0.0f;
        float px = c[3 * i + 0], py = c[3 * i + 1], pz = c[3 * i + 2];
        cnt += m;
        sx += m * px;  sy += m * py;  sz += m * pz;
        sxx += m * px * px;  syy += m * py * py;  szz += m * pz * pz;
    }
    for (int off = 32; off > 0; off >>= 1) {
        cnt += __shfl_down(cnt, off);
        sx  += __shfl_down(sx, off);
        sy  += __shfl_down(sy, off);
        sz  += __shfl_down(sz, off);
        sxx += __shfl_down(sxx, off);
        syy += __shfl_down(syy, off);
        szz += __shfl_down(szz, off);
    }
    __shared__ float sb[4][7];
    const int lane = tid & 63, w = tid >> 6;
    if (lane == 0) {
        sb[w][0] = cnt; sb[w][1] = sx; sb[w][2] = sy; sb[w][3] = sz;
        sb[w][4] = sxx; sb[w][5] = syy; sb[w][6] = szz;
    }
    __syncthreads();
    if (tid == 0) {
        float C = 0, SX = 0, SY = 0, SZ = 0, SXX = 0, SYY = 0, SZZ = 0;
        for (int i = 0; i < 4; i++) {
            C += sb[i][0]; SX += sb[i][1]; SY += sb[i][2]; SZ += sb[i][3];
            SXX += sb[i][4]; SYY += sb[i][5]; SZZ += sb[i][6];
        }
        float safe = fmaxf(C, 1.0f);
        float mx = SX / safe, my = SY / safe, mz = SZ / safe;
        float ssc = (SXX - C * mx * mx) + (SYY - C * my * my) + (SZZ - C * mz * mz);
        float npairs = C * (C - 1.0f) * 0.5f;
        float denom = fmaxf(npairs, 1.0f) * 3.0f;
        wsreg[r] = (C > 1.0f) ? (2.0f * ssc / denom) : 0.0f;
    }
}

// ---------------- K2: fused spatial (block owns 16 queries, no grid sync) ----------------
__global__ __launch_bounds__(256, 4) void spatial_kernel(const float* __restrict__ c,
                                                         const float* __restrict__ x,
                                                         const float4* __restrict__ pre,
                                                         float* __restrict__ spart) {
    __shared__ float dA[QPB][80];
    __shared__ unsigned short iA[QPB][80];
    __shared__ float dL[QPB][4][5];
    __shared__ unsigned short iL[QPB][4][5];
    __shared__ float dS[QPB][5];
    __shared__ unsigned short iS[QPB][5];
    __shared__ float tauS[QPB];
    __shared__ float wsum[4];

    const int tid = threadIdx.x;
    const int blk = blockIdx.x;
    const int qi = tid & 15;     // query within block
    const int ci = tid >> 4;     // chunk within query (wave holds 4 distinct ci)
    const int q = blk * QPB + qi;
    const float qx = x[3 * q + 0], qy = x[3 * q + 1], qz = x[3 * q + 2];

    // ---- Phase A: sample scan, unconditional top-5 over 128 points ----
    {
        float s0 = inf32(), s1 = inf32(), s2 = inf32(), s3 = inf32(), s4 = inf32();
        int i0 = 0, i1 = 0, i2 = 0, i3 = 0, i4 = 0;
        const int j0 = ci * SUBLEN;
        for (int jb = j0; jb < j0 + SUBLEN; jb += 8) {
            float dt[8];
#pragma unroll
            for (int u = 0; u < 8; ++u) {
                float4 pj = pre[jb + u];
                dt[u] = fmaf(pj.x, qx, fmaf(pj.y, qy, fmaf(pj.z, qz, pj.w)));
            }
#pragma unroll
            for (int u = 0; u < 8; ++u) {
                int j = jb + u;
                float nv = (j != q) ? dt[u] : inf32();
                INS5(nv, j);
            }
        }
        dA[qi][ci * 5 + 0] = s0; iA[qi][ci * 5 + 0] = (unsigned short)i0;
        dA[qi][ci * 5 + 1] = s1; iA[qi][ci * 5 + 1] = (unsigned short)i1;
        dA[qi][ci * 5 + 2] = s2; iA[qi][ci * 5 + 2] = (unsigned short)i2;
        dA[qi][ci * 5 + 3] = s3; iA[qi][ci * 5 + 3] = (unsigned short)i3;
        dA[qi][ci * 5 + 4] = s4; iA[qi][ci * 5 + 4] = (unsigned short)i4;
    }
    __syncthreads();

    // ---- A-merge level 1: 4 threads/query, 20 candidates each ----
    if (tid < 64) {
        const int qq = tid & 15, g = tid >> 4;
        float s0 = inf32(), s1 = inf32(), s2 = inf32(), s3 = inf32(), s4 = inf32();
        int i0 = 0, i1 = 0, i2 = 0, i3 = 0, i4 = 0;
#pragma unroll
        for (int n = 0; n < 20; ++n) {
            float nv = dA[qq][g * 20 + n];
            int jj = (int)iA[qq][g * 20 + n];
            INS5(nv, jj);
        }
        dL[qq][g][0] = s0; iL[qq][g][0] = (unsigned short)i0;
        dL[qq][g][1] = s1; iL[qq][g][1] = (unsigned short)i1;
        dL[qq][g][2] = s2; iL[qq][g][2] = (unsigned short)i2;
        dL[qq][g][3] = s3; iL[qq][g][3] = (unsigned short)i3;
        dL[qq][g][4] = s4; iL[qq][g][4] = (unsigned short)i4;
    }
    __syncthreads();

    // ---- A-merge level 2: 1 thread/query -> seeds + bumped tau ----
    if (tid < 16) {
        const int qq = tid;
        float s0 = inf32(), s1 = inf32(), s2 = inf32(), s3 = inf32(), s4 = inf32();
        int i0 = 0, i1 = 0, i2 = 0, i3 = 0, i4 = 0;
#pragma unroll
        for (int g = 0; g < 4; ++g)
#pragma unroll
            for (int k = 0; k < 5; ++k) {
                float nv = dL[qq][g][k];
                int jj = (int)iL[qq][g][k];
                INS5(nv, jj);
            }
        dS[qq][0] = s0; iS[qq][0] = (unsigned short)i0;
        dS[qq][1] = s1; iS[qq][1] = (unsigned short)i1;
        dS[qq][2] = s2; iS[qq][2] = (unsigned short)i2;
        dS[qq][3] = s3; iS[qq][3] = (unsigned short)i3;
        dS[qq][4] = s4; iS[qq][4] = (unsigned short)i4;
        int b = __float_as_int(s4);          // bump 1 ulp: admit d == tau ties
        b += (b >= 0) ? 1 : -1;
        tauS[qq] = __int_as_float(b);
    }
    __syncthreads();

    // ---- Phase B: tau-filtered scan of remaining 896 points per thread ----
    {
        const float t = tauS[qi];
        float s0 = t, s1 = t, s2 = t, s3 = t, s4 = t;
        int i0 = SENT, i1 = SENT, i2 = SENT, i3 = SENT, i4 = SENT;
        const int jbase = SAMPLE + ci * CHUNK;
        for (int jb = jbase; jb < jbase + CHUNK; jb += 8) {
            float dt[8];
#pragma unroll
            for (int u = 0; u < 8; ++u) {
                float4 pj = pre[jb + u];
                dt[u] = fmaf(pj.x, qx, fmaf(pj.y, qy, fmaf(pj.z, qz, pj.w)));
            }
#pragma unroll
            for (int u = 0; u < 8; ++u) {
                if (__any(dt[u] < s4)) {     // rare wave-correlated branch
                    int j = jb + u;
                    bool p = (dt[u] < s4) && (j != q);
                    float nv = p ? dt[u] : inf32();
                    INS5(nv, j);
                }
            }
        }
        dA[qi][ci * 5 + 0] = s0; iA[qi][ci * 5 + 0] = (unsigned short)i0;
        dA[qi][ci * 5 + 1] = s1; iA[qi][ci * 5 + 1] = (unsigned short)i1;
        dA[qi][ci * 5 + 2] = s2; iA[qi][ci * 5 + 2] = (unsigned short)i2;
        dA[qi][ci * 5 + 3] = s3; iA[qi][ci * 5 + 3] = (unsigned short)i3;
        dA[qi][ci * 5 + 4] = s4; iA[qi][ci * 5 + 4] = (unsigned short)i4;
    }
    __syncthreads();

    // ---- C-merge level 1 ----
    if (tid < 64) {
        const int qq = tid & 15, g = tid >> 4;
        float s0 = inf32(), s1 = inf32(), s2 = inf32(), s3 = inf32(), s4 = inf32();
        int i0 = SENT, i1 = SENT, i2 = SENT, i3 = SENT, i4 = SENT;
#pragma unroll
        for (int n = 0; n < 20; ++n) {
            float nv = dA[qq][g * 20 + n];
            int jj = (int)iA[qq][g * 20 + n];
            INS5(nv, jj);
        }
        dL[qq][g][0] = s0; iL[qq][g][0] = (unsigned short)i0;
        dL[qq][g][1] = s1; iL[qq][g][1] = (unsigned short)i1;
        dL[qq][g][2] = s2; iL[qq][g][2] = (unsigned short)i2;
        dL[qq][g][3] = s3; iL[qq][g][3] = (unsigned short)i3;
        dL[qq][g][4] = s4; iL[qq][g][4] = (unsigned short)i4;
    }
    __syncthreads();

    // ---- C-merge level 2 (seeds FIRST: smaller j wins ties) + c-loss ----
    float acc = 0.f;
    if (tid < 16) {
        const int qq = tid;
        float s0 = inf32(), s1 = inf32(), s2 = inf32(), s3 = inf32(), s4 = inf32();
        int i0 = 0, i1 = 0, i2 = 0, i3 = 0, i4 = 0;
#pragma unroll
        for (int k = 0; k < 5; ++k) {
            float nv = dS[qq][k];
            int jj = (int)iS[qq][k];
            INS5(nv, jj);
        }
#pragma unroll
        for (int g = 0; g < 4; ++g)
#pragma unroll
            for (int k = 0; k < 5; ++k) {
                float nv = dL[qq][g][k];
                int jj = (int)iL[qq][g][k];
                INS5(nv, jj);
            }
        const int qg = blk * QPB + qq;
        const float cx = c[3 * qg + 0], cy = c[3 * qg + 1], cz = c[3 * qg + 2];
        int ks[5] = {i0, i1, i2, i3, i4};
#pragma unroll
        for (int n = 0; n < KNB; ++n) {
            int nb = ks[n];
            float dx = cx - c[3 * nb + 0];
            float dy = cy - c[3 * nb + 1];
            float dz = cz - c[3 * nb + 2];
            acc += dx * dx + dy * dy + dz * dz;
        }
    }
    // lanes 0..15 of wave 0 hold sums; all other lanes hold 0
    acc += __shfl_down(acc, 8);
    acc += __shfl_down(acc, 4);
    acc += __shfl_down(acc, 2);
    acc += __shfl_down(acc, 1);
    {
        const int lane = tid & 63, w = tid >> 6;
        if (lane == 0) wsum[w] = acc;
    }
    __syncthreads();
    if (tid == 0) spart[blk] = wsum[0] + wsum[1] + wsum[2] + wsum[3];
}

// ---------------- K3: finalize ----------------
__global__ __launch_bounds__(256) void finalize_kernel(const float* __restrict__ wsreg,
                                                       const float* __restrict__ spart,
                                                       float* __restrict__ out) {
    const int tid = threadIdx.x;
    float s = 0.f;
    for (int i = tid; i < NBLK; i += 256) s += spart[i];
    float r = (tid < NREG) ? wsreg[tid] : 0.f;
    for (int off = 32; off > 0; off >>= 1) {
        s += __shfl_down(s, off);
        r += __shfl_down(r, off);
    }
    __shared__ float sb[4][2];
    const int lane = tid & 63, w = tid >> 6;
    if (lane == 0) { sb[w][0] = s; sb[w][1] = r; }
    __syncthreads();
    if (tid == 0) {
        float S = sb[0][0] + sb[1][0] + sb[2][0] + sb[3][0];
        float R = sb[0][1] + sb[1][1] + sb[2][1] + sb[3][1];
        float spatial_mean = S / (float)(B_N * KNB);
        out[0] = 0.02f * R + 0.0005f * (spatial_mean / 3.0f);
    }
}

extern "C" void kernel_launch(void* const* d_in, const int* in_sizes, int n_in,
                              void* d_out, int out_size, void* d_ws, size_t ws_size,
                              hipStream_t stream) {
    const float* c  = (const float*)d_in[0];   // c_points   [16384,3] f32
    const float* x  = (const float*)d_in[1];   // coords_std [16384,3] f32
    const int* ids  = (const int*)d_in[2];     // region_ids [16384] i32
    float* out = (float*)d_out;

    char* ws = (char*)d_ws;
    float4* pre = (float4*)ws;                      // 256 KiB
    float* wsreg = (float*)(ws + (size_t)B_N * 16); // 64 f
    float* spart = wsreg + NREG;                    // 1024 f

    hipLaunchKernelGGL(prep_kernel, dim3(128), dim3(256), 0, stream, c, x, ids, pre, wsreg);
    hipLaunchKernelGGL(spatial_kernel, dim3(NBLK), dim3(256), 0, stream, c, x, pre, spart);
    hipLaunchKernelGGL(finalize_kernel, dim3(1), dim3(256), 0, stream, wsreg, spart, out);
}

// Round 6
// 143.594 us; speedup vs baseline: 5.7082x; 1.0467x over previous
//
#include <hip/hip_runtime.h>
#include <stdint.h>

#define B_N    16384
#define NREG   64
#define KNB    5
#define SAMPLE 4096
#define NSUB   16
#define SUBLEN (SAMPLE / NSUB)       // 256 sample points per tau thread
#define NCH    16
#define CHLEN  (B_N / NCH)           // 1024 scan points per spatial thread
#define SENT   0xFFFF

static __device__ __forceinline__ float inf32() { return __int_as_float(0x7f800000); }
static __device__ __forceinline__ float med3(float a, float b, float c) {
    return __builtin_amdgcn_fmed3f(a, b, c);
}

// values-only sorted-insert into ascending s0..s4 (5 VALU: 4 med3 + 1 min).
// descending update order uses pre-update neighbors.
#define MINS5(nv)                      \
    {                                  \
        s4 = med3(s3, s4, (nv));       \
        s3 = med3(s2, s3, (nv));       \
        s2 = med3(s1, s2, (nv));       \
        s1 = med3(s0, s1, (nv));       \
        s0 = fminf(s0, (nv));          \
    }

// indexed flat 5-slot sorted-insert; strict < => ties keep earlier insert (smaller j)
#define INS5(nv, jj)                                                        \
    {                                                                       \
        bool c4 = (nv) < s4, c3 = (nv) < s3, c2 = (nv) < s2,                \
             c1 = (nv) < s1, c0 = (nv) < s0;                                \
        s4 = c3 ? s3 : (c4 ? (nv) : s4);  i4 = c3 ? i3 : (c4 ? (jj) : i4);  \
        s3 = c2 ? s2 : (c3 ? (nv) : s3);  i3 = c2 ? i2 : (c3 ? (jj) : i3);  \
        s2 = c1 ? s1 : (c2 ? (nv) : s2);  i2 = c1 ? i1 : (c2 ? (jj) : i2);  \
        s1 = c0 ? s0 : (c1 ? (nv) : s1);  i1 = c0 ? i0 : (c1 ? (jj) : i1);  \
        s0 = c0 ? (nv) : s0;              i0 = c0 ? (jj) : i0;              \
    }

// ---------------- K1: pre (blocks 0..63) + region (blocks 64..127) ----------------
__global__ __launch_bounds__(256) void prep_kernel(const float* __restrict__ c,
                                                   const float* __restrict__ x,
                                                   const int* __restrict__ ids,
                                                   float4* __restrict__ pre,
                                                   float* __restrict__ wsreg,
                                                   int* __restrict__ counter) {
    const int blk = blockIdx.x;
    const int tid = threadIdx.x;
    if (blk < 64) {
        if (blk == 0 && tid == 0) *counter = 0;   // re-zero every call (graph replay)
        int j = blk * 256 + tid;
        float jx = x[3 * j + 0], jy = x[3 * j + 1], jz = x[3 * j + 2];
        pre[j] = make_float4(-2.f * jx, -2.f * jy, -2.f * jz,
                             jx * jx + jy * jy + jz * jz);
        return;
    }
    const int r = blk - 64;
    float cnt = 0.f, sx = 0.f, sy = 0.f, sz = 0.f, sxx = 0.f, syy = 0.f, szz = 0.f;
    for (int i = tid; i < B_N; i += 256) {
        int id = ids[i];
        float m = (id == r) ? 1.0f : 0.0f;
        float px = c[3 * i + 0], py = c[3 * i + 1], pz = c[3 * i + 2];
        cnt += m;
        sx += m * px;  sy += m * py;  sz += m * pz;
        sxx += m * px * px;  syy += m * py * py;  szz += m * pz * pz;
    }
    for (int off = 32; off > 0; off >>= 1) {
        cnt += __shfl_down(cnt, off);
        sx  += __shfl_down(sx, off);
        sy  += __shfl_down(sy, off);
        sz  += __shfl_down(sz, off);
        sxx += __shfl_down(sxx, off);
        syy += __shfl_down(syy, off);
        szz += __shfl_down(szz, off);
    }
    __shared__ float sb[4][7];
    const int lane = tid & 63, w = tid >> 6;
    if (lane == 0) {
        sb[w][0] = cnt; sb[w][1] = sx; sb[w][2] = sy; sb[w][3] = sz;
        sb[w][4] = sxx; sb[w][5] = syy; sb[w][6] = szz;
    }
    __syncthreads();
    if (tid == 0) {
        float C = 0, SX = 0, SY = 0, SZ = 0, SXX = 0, SYY = 0, SZZ = 0;
        for (int i = 0; i < 4; i++) {
            C += sb[i][0]; SX += sb[i][1]; SY += sb[i][2]; SZ += sb[i][3];
            SXX += sb[i][4]; SYY += sb[i][5]; SZZ += sb[i][6];
        }
        float safe = fmaxf(C, 1.0f);
        float mx = SX / safe, my = SY / safe, mz = SZ / safe;
        float ssc = (SXX - C * mx * mx) + (SYY - C * my * my) + (SZZ - C * mz * mz);
        float npairs = C * (C - 1.0f) * 0.5f;
        float denom = fmaxf(npairs, 1.0f) * 3.0f;
        wsreg[r] = (C > 1.0f) ? (2.0f * ssc / denom) : 0.0f;
    }
}

// ---------------- K2: sample scan, values-only top-5 via med3 ----------------
__global__ __launch_bounds__(256) void tau_scan_kernel(const float4* __restrict__ pre,
                                                       float* __restrict__ tauv) {
    const int tid = threadIdx.x;
    const int qb = blockIdx.x & 63;
    const int sub = blockIdx.x >> 6;          // 0..15
    const int q = qb * 256 + tid;
    const float4 pq = pre[q];
    const float qx = -0.5f * pq.x, qy = -0.5f * pq.y, qz = -0.5f * pq.z;

    float s0 = inf32(), s1 = inf32(), s2 = inf32(), s3 = inf32(), s4 = inf32();

    const int j0 = sub * SUBLEN;
    for (int jb = j0; jb < j0 + SUBLEN; jb += 8) {
        float dt[8];
#pragma unroll
        for (int u = 0; u < 8; ++u) {
            float4 pj = pre[jb + u];          // wave-uniform -> scalar loads
            dt[u] = fmaf(pj.x, qx, fmaf(pj.y, qy, fmaf(pj.z, qz, pj.w)));
        }
#pragma unroll
        for (int u = 0; u < 8; ++u) {
            float nv = ((jb + u) != q) ? dt[u] : inf32();   // self-exclusion
            MINS5(nv);
        }
    }
    // transposed store: coalesced across lanes (stride-1 in q)
    tauv[(sub * 5 + 0) * B_N + q] = s0;
    tauv[(sub * 5 + 1) * B_N + q] = s1;
    tauv[(sub * 5 + 2) * B_N + q] = s2;
    tauv[(sub * 5 + 3) * B_N + q] = s3;
    tauv[(sub * 5 + 4) * B_N + q] = s4;
}

// ---------------- K3: inline tau-merge + filtered scan of a 1024-chunk ----------------
__global__ __launch_bounds__(256) void spatial_kernel(const float4* __restrict__ pre,
                                                      const float* __restrict__ tauv,
                                                      unsigned short* __restrict__ cand) {
    const int tid = threadIdx.x;
    const int qb = blockIdx.x & 63;
    const int ch = blockIdx.x >> 6;           // 0..15
    const int q = qb * 256 + tid;
    const float4 pq = pre[q];
    const float qx = -0.5f * pq.x, qy = -0.5f * pq.y, qz = -0.5f * pq.z;

    // merge the 80 sample top-5 values -> tau (exact 5th-smallest of sample)
    float s0 = inf32(), s1 = inf32(), s2 = inf32(), s3 = inf32(), s4 = inf32();
#pragma unroll 8
    for (int n = 0; n < NSUB * 5; ++n) {
        float v = tauv[n * B_N + q];          // coalesced
        MINS5(v);
    }
    int b = __float_as_int(s4);               // bump 1 ulp: admit d == tau ties
    b += (b >= 0) ? 1 : -1;
    const float tau = __int_as_float(b);

    // tau-seeded filtered scan (covers ALL points; sample re-admits itself)
    s0 = tau; s1 = tau; s2 = tau; s3 = tau; s4 = tau;
    int i0 = SENT, i1 = SENT, i2 = SENT, i3 = SENT, i4 = SENT;

    const int jbase = ch * CHLEN;
    for (int jb = jbase; jb < jbase + CHLEN; jb += 8) {
        float dt[8];
#pragma unroll
        for (int u = 0; u < 8; ++u) {
            float4 pj = pre[jb + u];          // wave-uniform -> scalar loads
            dt[u] = fmaf(pj.x, qx, fmaf(pj.y, qy, fmaf(pj.z, qz, pj.w)));
        }
#pragma unroll
        for (int u = 0; u < 8; ++u) {
            if (__any(dt[u] < s4)) {          // ~7.5% wave-correlated trigger
                int j = jb + u;
                bool p = (dt[u] < s4) && (j != q);
                float nv = p ? dt[u] : inf32();
                INS5(nv, j);
            }
        }
    }
    // transposed store: coalesced
    cand[(ch * 5 + 0) * B_N + q] = (unsigned short)i0;
    cand[(ch * 5 + 1) * B_N + q] = (unsigned short)i1;
    cand[(ch * 5 + 2) * B_N + q] = (unsigned short)i2;
    cand[(ch * 5 + 3) * B_N + q] = (unsigned short)i3;
    cand[(ch * 5 + 4) * B_N + q] = (unsigned short)i4;
}

// ---------------- K4: final merge + c-loss + last-block finalize ----------------
__global__ __launch_bounds__(256) void merge_kernel(const float* __restrict__ c,
                                                    const float4* __restrict__ pre,
                                                    const unsigned short* __restrict__ cand,
                                                    const float* __restrict__ wsreg,
                                                    float* __restrict__ spart,
                                                    int* __restrict__ counter,
                                                    float* __restrict__ out) {
    const int tid = threadIdx.x;
    const int blk = blockIdx.x;
    const int q = blk * 256 + tid;
    const float4 pq = pre[q];
    const float qx = -0.5f * pq.x, qy = -0.5f * pq.y, qz = -0.5f * pq.z;

    float s0 = inf32(), s1 = inf32(), s2 = inf32(), s3 = inf32(), s4 = inf32();
    int i0 = 0, i1 = 0, i2 = 0, i3 = 0, i4 = 0;

    // chunks ascending, slots ascending => tie-break keeps smallest j (matches top_k)
#pragma unroll 8
    for (int n = 0; n < NCH * 5; ++n) {
        int cd = (int)cand[n * B_N + q];      // coalesced
        int safe = cd & 0x3FFF;               // SENT -> valid addr, masked below
        float4 pj = pre[safe];
        float d = fmaf(pj.x, qx, fmaf(pj.y, qy, fmaf(pj.z, qz, pj.w)));
        float nv = (cd != SENT) ? d : inf32();
        INS5(nv, safe);
    }

    const float cx = c[3 * q + 0], cy = c[3 * q + 1], cz = c[3 * q + 2];
    float acc = 0.f;
    int ks[5] = {i0, i1, i2, i3, i4};
#pragma unroll
    for (int n = 0; n < KNB; ++n) {
        int nb = ks[n];
        float dx = cx - c[3 * nb + 0];
        float dy = cy - c[3 * nb + 1];
        float dz = cz - c[3 * nb + 2];
        acc += dx * dx + dy * dy + dz * dz;
    }

    for (int off = 32; off > 0; off >>= 1) acc += __shfl_down(acc, off);
    __shared__ float wsum[4];
    __shared__ int last;
    const int lane = tid & 63, w = tid >> 6;
    if (lane == 0) wsum[w] = acc;
    __syncthreads();
    if (tid == 0) {
        float bs = wsum[0] + wsum[1] + wsum[2] + wsum[3];
        atomicExch(&spart[blk], bs);          // device-scope visible store
        __threadfence();
        int old = atomicAdd(counter, 1);
        last = (old == 63);
    }
    __syncthreads();
    if (last) {
        // fixed-order reduction => bitwise deterministic regardless of which block runs it
        float s = (tid < 64) ? atomicAdd(&spart[tid], 0.0f) : 0.f;   // device-scope read
        float r = (tid < 64) ? wsreg[tid] : 0.f;
        for (int off = 32; off > 0; off >>= 1) {
            s += __shfl_down(s, off);
            r += __shfl_down(r, off);
        }
        if (tid == 0) {
            float spatial_mean = s / (float)(B_N * KNB);
            out[0] = 0.02f * r + 0.0005f * (spatial_mean / 3.0f);
        }
    }
}

extern "C" void kernel_launch(void* const* d_in, const int* in_sizes, int n_in,
                              void* d_out, int out_size, void* d_ws, size_t ws_size,
                              hipStream_t stream) {
    const float* c  = (const float*)d_in[0];   // c_points   [16384,3] f32
    const float* x  = (const float*)d_in[1];   // coords_std [16384,3] f32
    const int* ids  = (const int*)d_in[2];     // region_ids [16384] i32
    float* out = (float*)d_out;

    char* ws = (char*)d_ws;
    float4* pre = (float4*)ws;                                   // 256 KiB
    float* tauv = (float*)(ws + (size_t)B_N * 16);               // 80*B_N f = 5.25 MiB
    unsigned short* cand =
        (unsigned short*)(ws + (size_t)B_N * 16 + (size_t)NSUB * 5 * B_N * 4);  // 2.62 MiB
    float* wsreg = (float*)((char*)cand + (size_t)NCH * 5 * B_N * 2);  // 64 f
    float* spart = wsreg + NREG;                                 // 64 f
    int* counter = (int*)(spart + 64);                           // 1 int

    hipLaunchKernelGGL(prep_kernel, dim3(128), dim3(256), 0, stream, c, x, ids, pre, wsreg, counter);
    hipLaunchKernelGGL(tau_scan_kernel, dim3(64 * NSUB), dim3(256), 0, stream, pre, tauv);
    hipLaunchKernelGGL(spatial_kernel, dim3(64 * NCH), dim3(256), 0, stream, pre, tauv, cand);
    hipLaunchKernelGGL(merge_kernel, dim3(64), dim3(256), 0, stream, c, pre, cand, wsreg, spart, counter, out);
}

// Round 7
// 122.342 us; speedup vs baseline: 6.6997x; 1.1737x over previous
//
#include <hip/hip_runtime.h>
#include <stdint.h>

#define B_N    16384
#define NREG   64
#define KNB    5
#define SAMPLE 4096
#define NSUB   16
#define SUBLEN (SAMPLE / NSUB)       // 256 sample points per tau thread
#define NCH    32
#define CHLEN  (B_N / NCH)           // 512 scan points per spatial thread
#define MRGBLK 256                   // merge blocks (64 q each, 4 threads/q)
#define SENT   0xFFFF

static __device__ __forceinline__ float inf32() { return __int_as_float(0x7f800000); }
static __device__ __forceinline__ float med3(float a, float b, float c) {
    return __builtin_amdgcn_fmed3f(a, b, c);
}

// values-only sorted-insert into ascending s0..s4 (4 med3 + 1 min)
#define MINS5(nv)                      \
    {                                  \
        s4 = med3(s3, s4, (nv));       \
        s3 = med3(s2, s3, (nv));       \
        s2 = med3(s1, s2, (nv));       \
        s1 = med3(s0, s1, (nv));       \
        s0 = fminf(s0, (nv));          \
    }

// indexed flat 5-slot sorted-insert; strict < => ties keep earlier insert (smaller j)
#define INS5(nv, jj)                                                        \
    {                                                                       \
        bool c4 = (nv) < s4, c3 = (nv) < s3, c2 = (nv) < s2,                \
             c1 = (nv) < s1, c0 = (nv) < s0;                                \
        s4 = c3 ? s3 : (c4 ? (nv) : s4);  i4 = c3 ? i3 : (c4 ? (jj) : i4);  \
        s3 = c2 ? s2 : (c3 ? (nv) : s3);  i3 = c2 ? i2 : (c3 ? (jj) : i3);  \
        s2 = c1 ? s1 : (c2 ? (nv) : s2);  i2 = c1 ? i1 : (c2 ? (jj) : i2);  \
        s1 = c0 ? s0 : (c1 ? (nv) : s1);  i1 = c0 ? i0 : (c1 ? (jj) : i1);  \
        s0 = c0 ? (nv) : s0;              i0 = c0 ? (jj) : i0;              \
    }

// ---------------- K1: pre (blocks 0..63) + region (blocks 64..127) ----------------
__global__ __launch_bounds__(256) void prep_kernel(const float* __restrict__ c,
                                                   const float* __restrict__ x,
                                                   const int* __restrict__ ids,
                                                   float4* __restrict__ pre,
                                                   float* __restrict__ wsreg,
                                                   int* __restrict__ counter) {
    const int blk = blockIdx.x;
    const int tid = threadIdx.x;
    if (blk < 64) {
        if (blk == 0 && tid == 0) *counter = 0;   // re-zero every call (graph replay)
        int j = blk * 256 + tid;
        float jx = x[3 * j + 0], jy = x[3 * j + 1], jz = x[3 * j + 2];
        pre[j] = make_float4(-2.f * jx, -2.f * jy, -2.f * jz,
                             jx * jx + jy * jy + jz * jz);
        return;
    }
    const int r = blk - 64;
    float cnt = 0.f, sx = 0.f, sy = 0.f, sz = 0.f, sxx = 0.f, syy = 0.f, szz = 0.f;
    for (int i = tid; i < B_N; i += 256) {
        int id = ids[i];
        float m = (id == r) ? 1.0f : 0.0f;
        float px = c[3 * i + 0], py = c[3 * i + 1], pz = c[3 * i + 2];
        cnt += m;
        sx += m * px;  sy += m * py;  sz += m * pz;
        sxx += m * px * px;  syy += m * py * py;  szz += m * pz * pz;
    }
    for (int off = 32; off > 0; off >>= 1) {
        cnt += __shfl_down(cnt, off);
        sx  += __shfl_down(sx, off);
        sy  += __shfl_down(sy, off);
        sz  += __shfl_down(sz, off);
        sxx += __shfl_down(sxx, off);
        syy += __shfl_down(syy, off);
        szz += __shfl_down(szz, off);
    }
    __shared__ float sb[4][7];
    const int lane = tid & 63, w = tid >> 6;
    if (lane == 0) {
        sb[w][0] = cnt; sb[w][1] = sx; sb[w][2] = sy; sb[w][3] = sz;
        sb[w][4] = sxx; sb[w][5] = syy; sb[w][6] = szz;
    }
    __syncthreads();
    if (tid == 0) {
        float C = 0, SX = 0, SY = 0, SZ = 0, SXX = 0, SYY = 0, SZZ = 0;
        for (int i = 0; i < 4; i++) {
            C += sb[i][0]; SX += sb[i][1]; SY += sb[i][2]; SZ += sb[i][3];
            SXX += sb[i][4]; SYY += sb[i][5]; SZZ += sb[i][6];
        }
        float safe = fmaxf(C, 1.0f);
        float mx = SX / safe, my = SY / safe, mz = SZ / safe;
        float ssc = (SXX - C * mx * mx) + (SYY - C * my * my) + (SZZ - C * mz * mz);
        float npairs = C * (C - 1.0f) * 0.5f;
        float denom = fmaxf(npairs, 1.0f) * 3.0f;
        wsreg[r] = (C > 1.0f) ? (2.0f * ssc / denom) : 0.0f;
    }
}

// ---------------- K2: sample scan, values-only top-5 via med3 ----------------
__global__ __launch_bounds__(256) void tau_scan_kernel(const float4* __restrict__ pre,
                                                       float* __restrict__ tauv) {
    const int tid = threadIdx.x;
    const int qb = blockIdx.x & 63;
    const int sub = blockIdx.x >> 6;          // 0..15
    const int q = qb * 256 + tid;
    const float4 pq = pre[q];
    const float qx = -0.5f * pq.x, qy = -0.5f * pq.y, qz = -0.5f * pq.z;

    float s0 = inf32(), s1 = inf32(), s2 = inf32(), s3 = inf32(), s4 = inf32();

    const int j0 = sub * SUBLEN;
    for (int jb = j0; jb < j0 + SUBLEN; jb += 8) {
        float dt[8];
#pragma unroll
        for (int u = 0; u < 8; ++u) {
            float4 pj = pre[jb + u];          // wave-uniform -> scalar loads
            dt[u] = fmaf(pj.x, qx, fmaf(pj.y, qy, fmaf(pj.z, qz, pj.w)));
        }
#pragma unroll
        for (int u = 0; u < 8; ++u) {
            float nv = ((jb + u) != q) ? dt[u] : inf32();   // self-exclusion
            MINS5(nv);
        }
    }
    tauv[(sub * 5 + 0) * B_N + q] = s0;       // transposed: coalesced in q
    tauv[(sub * 5 + 1) * B_N + q] = s1;
    tauv[(sub * 5 + 2) * B_N + q] = s2;
    tauv[(sub * 5 + 3) * B_N + q] = s3;
    tauv[(sub * 5 + 4) * B_N + q] = s4;
}

// ---------------- K3: merge 80 sample values -> bumped tau[q] (once per q) ----------------
__global__ __launch_bounds__(256) void tau_merge_kernel(const float* __restrict__ tauv,
                                                        float* __restrict__ tau) {
    const int q = blockIdx.x * 256 + threadIdx.x;
    float s0 = inf32(), s1 = inf32(), s2 = inf32(), s3 = inf32(), s4 = inf32();
#pragma unroll 8
    for (int n = 0; n < NSUB * 5; ++n) {
        float v = tauv[n * B_N + q];          // coalesced
        MINS5(v);
    }
    int b = __float_as_int(s4);               // bump 1 ulp: admit d == tau ties
    b += (b >= 0) ? 1 : -1;
    tau[q] = __int_as_float(b);
}

// ---------------- K4: tau-filtered scan of a 512-chunk (covers ALL points) ----------------
__global__ __launch_bounds__(256) void spatial_kernel(const float4* __restrict__ pre,
                                                      const float* __restrict__ tau,
                                                      unsigned short* __restrict__ cand) {
    const int tid = threadIdx.x;
    const int qb = blockIdx.x & 63;
    const int ch = blockIdx.x >> 6;           // 0..31
    const int q = qb * 256 + tid;
    const float4 pq = pre[q];
    const float qx = -0.5f * pq.x, qy = -0.5f * pq.y, qz = -0.5f * pq.z;

    const float t = tau[q];
    float s0 = t, s1 = t, s2 = t, s3 = t, s4 = t;
    int i0 = SENT, i1 = SENT, i2 = SENT, i3 = SENT, i4 = SENT;

    const int jbase = ch * CHLEN;
    for (int jb = jbase; jb < jbase + CHLEN; jb += 8) {
        float dt[8];
#pragma unroll
        for (int u = 0; u < 8; ++u) {
            float4 pj = pre[jb + u];          // wave-uniform -> scalar loads
            dt[u] = fmaf(pj.x, qx, fmaf(pj.y, qy, fmaf(pj.z, qz, pj.w)));
        }
#pragma unroll
        for (int u = 0; u < 8; ++u) {
            if (__any(dt[u] < s4)) {          // ~7.5% wave-correlated trigger
                int j = jb + u;
                bool p = (dt[u] < s4) && (j != q);
                float nv = p ? dt[u] : inf32();
                INS5(nv, j);
            }
        }
    }
    cand[(ch * 5 + 0) * B_N + q] = (unsigned short)i0;   // transposed: coalesced
    cand[(ch * 5 + 1) * B_N + q] = (unsigned short)i1;
    cand[(ch * 5 + 2) * B_N + q] = (unsigned short)i2;
    cand[(ch * 5 + 3) * B_N + q] = (unsigned short)i3;
    cand[(ch * 5 + 4) * B_N + q] = (unsigned short)i4;
}

// ---------------- K5: final merge (4 threads/q) + c-loss + last-block finalize ----------------
__global__ __launch_bounds__(256) void merge_kernel(const float* __restrict__ c,
                                                    const float4* __restrict__ pre,
                                                    const unsigned short* __restrict__ cand,
                                                    const float* __restrict__ wsreg,
                                                    float* __restrict__ spart,
                                                    int* __restrict__ counter,
                                                    float* __restrict__ out) {
    const int tid = threadIdx.x;
    const int blk = blockIdx.x;
    const int qloc = tid >> 2;                // 0..63
    const int part = tid & 3;                 // 0..3 (chunks part*8 .. part*8+7)
    const int q = blk * 64 + qloc;
    const float4 pq = pre[q];
    const float qx = -0.5f * pq.x, qy = -0.5f * pq.y, qz = -0.5f * pq.z;

    __shared__ float dm[64][4][5];
    __shared__ unsigned short im[64][4][5];

    {
        float s0 = inf32(), s1 = inf32(), s2 = inf32(), s3 = inf32(), s4 = inf32();
        int i0 = SENT & 0x3FFF, i1 = i0, i2 = i0, i3 = i0, i4 = i0;
        const int n0 = part * (NCH / 4) * 5;  // 40 slots, chunk-ascending
#pragma unroll 8
        for (int n = n0; n < n0 + (NCH / 4) * 5; ++n) {
            int cd = (int)cand[n * B_N + q];
            int safe = cd & 0x3FFF;           // SENT -> valid addr, masked below
            float4 pj = pre[safe];
            float d = fmaf(pj.x, qx, fmaf(pj.y, qy, fmaf(pj.z, qz, pj.w)));
            float nv = (cd != SENT) ? d : inf32();
            INS5(nv, safe);
        }
        dm[qloc][part][0] = s0; im[qloc][part][0] = (unsigned short)i0;
        dm[qloc][part][1] = s1; im[qloc][part][1] = (unsigned short)i1;
        dm[qloc][part][2] = s2; im[qloc][part][2] = (unsigned short)i2;
        dm[qloc][part][3] = s3; im[qloc][part][3] = (unsigned short)i3;
        dm[qloc][part][4] = s4; im[qloc][part][4] = (unsigned short)i4;
    }
    __syncthreads();

    float acc = 0.f;
    if (part == 0) {
        float s0 = inf32(), s1 = inf32(), s2 = inf32(), s3 = inf32(), s4 = inf32();
        int i0 = 0, i1 = 0, i2 = 0, i3 = 0, i4 = 0;
#pragma unroll
        for (int p = 0; p < 4; ++p)           // ascending p = ascending chunks
#pragma unroll
            for (int k = 0; k < 5; ++k) {
                float nv = dm[qloc][p][k];
                int jj = (int)im[qloc][p][k];
                INS5(nv, jj);
            }
        const float cx = c[3 * q + 0], cy = c[3 * q + 1], cz = c[3 * q + 2];
        int ks[5] = {i0, i1, i2, i3, i4};
#pragma unroll
        for (int n = 0; n < KNB; ++n) {
            int nb = ks[n];
            float dx = cx - c[3 * nb + 0];
            float dy = cy - c[3 * nb + 1];
            float dz = cz - c[3 * nb + 2];
            acc += dx * dx + dy * dy + dz * dz;
        }
    }
    // acc nonzero on lanes == 0 mod 4; offsets 32,16,8,4 sum them onto lane 0
    acc += __shfl_down(acc, 32);
    acc += __shfl_down(acc, 16);
    acc += __shfl_down(acc, 8);
    acc += __shfl_down(acc, 4);
    __shared__ float wsum[4];
    __shared__ int last;
    const int lane = tid & 63, w = tid >> 6;
    if (lane == 0) wsum[w] = acc;
    __syncthreads();
    if (tid == 0) {
        float bs = wsum[0] + wsum[1] + wsum[2] + wsum[3];
        atomicExch(&spart[blk], bs);          // device-scope visible store
        __threadfence();
        int old = atomicAdd(counter, 1);
        last = (old == MRGBLK - 1);
    }
    __syncthreads();
    if (last) {
        // fixed-order reduction => bitwise deterministic regardless of which block runs it
        float s = atomicAdd(&spart[tid], 0.0f);          // device-scope read, 256 partials
        float r = (tid < NREG) ? wsreg[tid] : 0.f;
        for (int off = 32; off > 0; off >>= 1) {
            s += __shfl_down(s, off);
            r += __shfl_down(r, off);
        }
        __shared__ float fb[4];
        if (lane == 0) fb[w] = s;
        __syncthreads();
        if (tid == 0) {
            float S = fb[0] + fb[1] + fb[2] + fb[3];
            float spatial_mean = S / (float)(B_N * KNB);
            out[0] = 0.02f * r + 0.0005f * (spatial_mean / 3.0f);
        }
    }
}

extern "C" void kernel_launch(void* const* d_in, const int* in_sizes, int n_in,
                              void* d_out, int out_size, void* d_ws, size_t ws_size,
                              hipStream_t stream) {
    const float* c  = (const float*)d_in[0];   // c_points   [16384,3] f32
    const float* x  = (const float*)d_in[1];   // coords_std [16384,3] f32
    const int* ids  = (const int*)d_in[2];     // region_ids [16384] i32
    float* out = (float*)d_out;

    char* ws = (char*)d_ws;
    float4* pre = (float4*)ws;                                        // 256 KiB
    float* tauv = (float*)(ws + (size_t)B_N * 16);                    // 5.25 MiB
    unsigned short* cand =
        (unsigned short*)((char*)tauv + (size_t)NSUB * 5 * B_N * 4);  // 5.25 MiB
    float* tau = (float*)((char*)cand + (size_t)NCH * 5 * B_N * 2);   // 64 KiB
    float* wsreg = tau + B_N;                                         // 64 f
    float* spart = wsreg + NREG;                                      // 256 f
    int* counter = (int*)(spart + MRGBLK);                            // 1 int

    hipLaunchKernelGGL(prep_kernel, dim3(128), dim3(256), 0, stream, c, x, ids, pre, wsreg, counter);
    hipLaunchKernelGGL(tau_scan_kernel, dim3(64 * NSUB), dim3(256), 0, stream, pre, tauv);
    hipLaunchKernelGGL(tau_merge_kernel, dim3(64), dim3(256), 0, stream, tauv, tau);
    hipLaunchKernelGGL(spatial_kernel, dim3(64 * NCH), dim3(256), 0, stream, pre, tau, cand);
    hipLaunchKernelGGL(merge_kernel, dim3(MRGBLK), dim3(256), 0, stream, c, pre, cand, wsreg, spart, counter, out);
}

// Round 8
// 107.091 us; speedup vs baseline: 7.6539x; 1.1424x over previous
//
#include <hip/hip_runtime.h>
#include <stdint.h>

#define B_N    16384
#define NREG   64
#define KNB    5
#define SAMPLE 4096
#define NSUB   16
#define SUBLEN (SAMPLE / NSUB)       // 256 sample points per tau thread
#define NCH    32
#define CHLEN  (B_N / NCH)           // 512 scan points per spatial thread
#define MRGBLK 256                   // merge blocks (64 q each, 4 threads/q)
#define SENT   0xFFFF

static __device__ __forceinline__ float inf32() { return __int_as_float(0x7f800000); }
static __device__ __forceinline__ float med3(float a, float b, float c) {
    return __builtin_amdgcn_fmed3f(a, b, c);
}

// values-only sorted-insert into ascending s0..s4 (4 med3 + 1 min)
#define MINS5(nv)                      \
    {                                  \
        s4 = med3(s3, s4, (nv));       \
        s3 = med3(s2, s3, (nv));       \
        s2 = med3(s1, s2, (nv));       \
        s1 = med3(s0, s1, (nv));       \
        s0 = fminf(s0, (nv));          \
    }

// indexed flat 5-slot sorted-insert; strict < => ties keep earlier insert (smaller j)
#define INS5(nv, jj)                                                        \
    {                                                                       \
        bool c4 = (nv) < s4, c3 = (nv) < s3, c2 = (nv) < s2,                \
             c1 = (nv) < s1, c0 = (nv) < s0;                                \
        s4 = c3 ? s3 : (c4 ? (nv) : s4);  i4 = c3 ? i3 : (c4 ? (jj) : i4);  \
        s3 = c2 ? s2 : (c3 ? (nv) : s3);  i3 = c2 ? i2 : (c3 ? (jj) : i3);  \
        s2 = c1 ? s1 : (c2 ? (nv) : s2);  i2 = c1 ? i1 : (c2 ? (jj) : i2);  \
        s1 = c0 ? s0 : (c1 ? (nv) : s1);  i1 = c0 ? i0 : (c1 ? (jj) : i1);  \
        s0 = c0 ? (nv) : s0;              i0 = c0 ? (jj) : i0;              \
    }

// ---------------- K1: pre (blocks 0..63) + region (blocks 64..127) ----------------
__global__ __launch_bounds__(256) void prep_kernel(const float* __restrict__ c,
                                                   const float* __restrict__ x,
                                                   const int* __restrict__ ids,
                                                   float4* __restrict__ pre,
                                                   float* __restrict__ wsreg,
                                                   int* __restrict__ counter) {
    const int blk = blockIdx.x;
    const int tid = threadIdx.x;
    if (blk < 64) {
        if (blk == 0 && tid == 0) *counter = 0;   // re-zero every call (graph replay)
        int j = blk * 256 + tid;
        float jx = x[3 * j + 0], jy = x[3 * j + 1], jz = x[3 * j + 2];
        pre[j] = make_float4(-2.f * jx, -2.f * jy, -2.f * jz,
                             jx * jx + jy * jy + jz * jz);
        return;
    }
    const int r = blk - 64;
    float cnt = 0.f, sx = 0.f, sy = 0.f, sz = 0.f, sxx = 0.f, syy = 0.f, szz = 0.f;
    for (int i = tid; i < B_N; i += 256) {
        int id = ids[i];
        float m = (id == r) ? 1.0f : 0.0f;
        float px = c[3 * i + 0], py = c[3 * i + 1], pz = c[3 * i + 2];
        cnt += m;
        sx += m * px;  sy += m * py;  sz += m * pz;
        sxx += m * px * px;  syy += m * py * py;  szz += m * pz * pz;
    }
    for (int off = 32; off > 0; off >>= 1) {
        cnt += __shfl_down(cnt, off);
        sx  += __shfl_down(sx, off);
        sy  += __shfl_down(sy, off);
        sz  += __shfl_down(sz, off);
        sxx += __shfl_down(sxx, off);
        syy += __shfl_down(syy, off);
        szz += __shfl_down(szz, off);
    }
    __shared__ float sb[4][7];
    const int lane = tid & 63, w = tid >> 6;
    if (lane == 0) {
        sb[w][0] = cnt; sb[w][1] = sx; sb[w][2] = sy; sb[w][3] = sz;
        sb[w][4] = sxx; sb[w][5] = syy; sb[w][6] = szz;
    }
    __syncthreads();
    if (tid == 0) {
        float C = 0, SX = 0, SY = 0, SZ = 0, SXX = 0, SYY = 0, SZZ = 0;
        for (int i = 0; i < 4; i++) {
            C += sb[i][0]; SX += sb[i][1]; SY += sb[i][2]; SZ += sb[i][3];
            SXX += sb[i][4]; SYY += sb[i][5]; SZZ += sb[i][6];
        }
        float safe = fmaxf(C, 1.0f);
        float mx = SX / safe, my = SY / safe, mz = SZ / safe;
        float ssc = (SXX - C * mx * mx) + (SYY - C * my * my) + (SZZ - C * mz * mz);
        float npairs = C * (C - 1.0f) * 0.5f;
        float denom = fmaxf(npairs, 1.0f) * 3.0f;
        wsreg[r] = (C > 1.0f) ? (2.0f * ssc / denom) : 0.0f;
    }
}

// ---------------- K2: sample scan (LDS-staged tile), values-only top-5 ----------------
__global__ __launch_bounds__(256) void tau_scan_kernel(const float4* __restrict__ pre,
                                                       float* __restrict__ tauv) {
    __shared__ float4 tile[SUBLEN];           // 256 x 16 B = 4 KiB
    const int tid = threadIdx.x;
    const int qb = blockIdx.x & 63;
    const int sub = blockIdx.x >> 6;          // 0..15
    const int q = qb * 256 + tid;
    const int j0 = sub * SUBLEN;

    tile[tid] = pre[j0 + tid];                // coalesced, one float4 per thread
    const float4 pq = pre[q];
    const float qx = -0.5f * pq.x, qy = -0.5f * pq.y, qz = -0.5f * pq.z;
    __syncthreads();

    float s0 = inf32(), s1 = inf32(), s2 = inf32(), s3 = inf32(), s4 = inf32();

    for (int jb = 0; jb < SUBLEN; jb += 8) {
        float dt[8];
#pragma unroll
        for (int u = 0; u < 8; ++u) {
            float4 pj = tile[jb + u];         // wave-uniform -> LDS broadcast
            dt[u] = fmaf(pj.x, qx, fmaf(pj.y, qy, fmaf(pj.z, qz, pj.w)));
        }
#pragma unroll
        for (int u = 0; u < 8; ++u) {
            float nv = ((j0 + jb + u) != q) ? dt[u] : inf32();   // self-exclusion
            MINS5(nv);
        }
    }
    tauv[(sub * 5 + 0) * B_N + q] = s0;       // transposed: coalesced in q
    tauv[(sub * 5 + 1) * B_N + q] = s1;
    tauv[(sub * 5 + 2) * B_N + q] = s2;
    tauv[(sub * 5 + 3) * B_N + q] = s3;
    tauv[(sub * 5 + 4) * B_N + q] = s4;
}

// ---------------- K3: merge 80 sample values -> bumped tau[q] (once per q) ----------------
__global__ __launch_bounds__(256) void tau_merge_kernel(const float* __restrict__ tauv,
                                                        float* __restrict__ tau) {
    const int q = blockIdx.x * 256 + threadIdx.x;
    float s0 = inf32(), s1 = inf32(), s2 = inf32(), s3 = inf32(), s4 = inf32();
#pragma unroll 8
    for (int n = 0; n < NSUB * 5; ++n) {
        float v = tauv[n * B_N + q];          // coalesced
        MINS5(v);
    }
    int b = __float_as_int(s4);               // bump 1 ulp: admit d == tau ties
    b += (b >= 0) ? 1 : -1;
    tau[q] = __int_as_float(b);
}

// ---------------- K4: tau-filtered scan of an LDS-staged 512-chunk ----------------
__global__ __launch_bounds__(256) void spatial_kernel(const float4* __restrict__ pre,
                                                      const float* __restrict__ tau,
                                                      unsigned short* __restrict__ cand) {
    __shared__ float4 tile[CHLEN];            // 512 x 16 B = 8 KiB
    const int tid = threadIdx.x;
    const int qb = blockIdx.x & 63;
    const int ch = blockIdx.x >> 6;           // 0..31
    const int q = qb * 256 + tid;
    const int jbase = ch * CHLEN;

#pragma unroll
    for (int i = 0; i < CHLEN / 256; ++i)     // coalesced tile load
        tile[tid + i * 256] = pre[jbase + tid + i * 256];

    const float4 pq = pre[q];
    const float qx = -0.5f * pq.x, qy = -0.5f * pq.y, qz = -0.5f * pq.z;
    const float t = tau[q];
    __syncthreads();

    float s0 = t, s1 = t, s2 = t, s3 = t, s4 = t;
    int i0 = SENT, i1 = SENT, i2 = SENT, i3 = SENT, i4 = SENT;

    for (int jb = 0; jb < CHLEN; jb += 8) {
        float dt[8];
#pragma unroll
        for (int u = 0; u < 8; ++u) {
            float4 pj = tile[jb + u];         // wave-uniform -> LDS broadcast
            dt[u] = fmaf(pj.x, qx, fmaf(pj.y, qy, fmaf(pj.z, qz, pj.w)));
        }
#pragma unroll
        for (int u = 0; u < 8; ++u) {
            if (__any(dt[u] < s4)) {          // ~7.8% wave-correlated trigger
                int j = jbase + jb + u;
                bool p = (dt[u] < s4) && (j != q);
                float nv = p ? dt[u] : inf32();
                INS5(nv, j);
            }
        }
    }
    cand[(ch * 5 + 0) * B_N + q] = (unsigned short)i0;   // transposed: coalesced
    cand[(ch * 5 + 1) * B_N + q] = (unsigned short)i1;
    cand[(ch * 5 + 2) * B_N + q] = (unsigned short)i2;
    cand[(ch * 5 + 3) * B_N + q] = (unsigned short)i3;
    cand[(ch * 5 + 4) * B_N + q] = (unsigned short)i4;
}

// ---------------- K5: final merge (4 threads/q) + c-loss + last-block finalize ----------------
__global__ __launch_bounds__(256) void merge_kernel(const float* __restrict__ c,
                                                    const float4* __restrict__ pre,
                                                    const unsigned short* __restrict__ cand,
                                                    const float* __restrict__ wsreg,
                                                    float* __restrict__ spart,
                                                    int* __restrict__ counter,
                                                    float* __restrict__ out) {
    const int tid = threadIdx.x;
    const int blk = blockIdx.x;
    const int qloc = tid >> 2;                // 0..63
    const int part = tid & 3;                 // 0..3 (chunks part*8 .. part*8+7)
    const int q = blk * 64 + qloc;
    const float4 pq = pre[q];
    const float qx = -0.5f * pq.x, qy = -0.5f * pq.y, qz = -0.5f * pq.z;

    __shared__ float dm[64][4][5];
    __shared__ unsigned short im[64][4][5];

    {
        float s0 = inf32(), s1 = inf32(), s2 = inf32(), s3 = inf32(), s4 = inf32();
        int i0 = SENT & 0x3FFF, i1 = i0, i2 = i0, i3 = i0, i4 = i0;
        const int n0 = part * (NCH / 4) * 5;  // 40 slots, chunk-ascending
#pragma unroll 8
        for (int n = n0; n < n0 + (NCH / 4) * 5; ++n) {
            int cd = (int)cand[n * B_N + q];
            int safe = cd & 0x3FFF;           // SENT -> valid addr, masked below
            float4 pj = pre[safe];
            float d = fmaf(pj.x, qx, fmaf(pj.y, qy, fmaf(pj.z, qz, pj.w)));
            float nv = (cd != SENT) ? d : inf32();
            INS5(nv, safe);
        }
        dm[qloc][part][0] = s0; im[qloc][part][0] = (unsigned short)i0;
        dm[qloc][part][1] = s1; im[qloc][part][1] = (unsigned short)i1;
        dm[qloc][part][2] = s2; im[qloc][part][2] = (unsigned short)i2;
        dm[qloc][part][3] = s3; im[qloc][part][3] = (unsigned short)i3;
        dm[qloc][part][4] = s4; im[qloc][part][4] = (unsigned short)i4;
    }
    __syncthreads();

    float acc = 0.f;
    if (part == 0) {
        float s0 = inf32(), s1 = inf32(), s2 = inf32(), s3 = inf32(), s4 = inf32();
        int i0 = 0, i1 = 0, i2 = 0, i3 = 0, i4 = 0;
#pragma unroll
        for (int p = 0; p < 4; ++p)           // ascending p = ascending chunks
#pragma unroll
            for (int k = 0; k < 5; ++k) {
                float nv = dm[qloc][p][k];
                int jj = (int)im[qloc][p][k];
                INS5(nv, jj);
            }
        const float cx = c[3 * q + 0], cy = c[3 * q + 1], cz = c[3 * q + 2];
        int ks[5] = {i0, i1, i2, i3, i4};
#pragma unroll
        for (int n = 0; n < KNB; ++n) {
            int nb = ks[n];
            float dx = cx - c[3 * nb + 0];
            float dy = cy - c[3 * nb + 1];
            float dz = cz - c[3 * nb + 2];
            acc += dx * dx + dy * dy + dz * dz;
        }
    }
    // acc nonzero on lanes == 0 mod 4; offsets 32,16,8,4 sum them onto lane 0
    acc += __shfl_down(acc, 32);
    acc += __shfl_down(acc, 16);
    acc += __shfl_down(acc, 8);
    acc += __shfl_down(acc, 4);
    __shared__ float wsum[4];
    __shared__ int last;
    const int lane = tid & 63, w = tid >> 6;
    if (lane == 0) wsum[w] = acc;
    __syncthreads();
    if (tid == 0) {
        float bs = wsum[0] + wsum[1] + wsum[2] + wsum[3];
        atomicExch(&spart[blk], bs);          // device-scope visible store
        __threadfence();
        int old = atomicAdd(counter, 1);
        last = (old == MRGBLK - 1);
    }
    __syncthreads();
    if (last) {
        // fixed-order reduction => bitwise deterministic regardless of which block runs it
        float s = atomicAdd(&spart[tid], 0.0f);          // device-scope read, 256 partials
        float r = (tid < NREG) ? wsreg[tid] : 0.f;
        for (int off = 32; off > 0; off >>= 1) {
            s += __shfl_down(s, off);
            r += __shfl_down(r, off);
        }
        __shared__ float fb[4];
        if (lane == 0) fb[w] = s;
        __syncthreads();
        if (tid == 0) {
            float S = fb[0] + fb[1] + fb[2] + fb[3];
            float spatial_mean = S / (float)(B_N * KNB);
            out[0] = 0.02f * r + 0.0005f * (spatial_mean / 3.0f);
        }
    }
}

extern "C" void kernel_launch(void* const* d_in, const int* in_sizes, int n_in,
                              void* d_out, int out_size, void* d_ws, size_t ws_size,
                              hipStream_t stream) {
    const float* c  = (const float*)d_in[0];   // c_points   [16384,3] f32
    const float* x  = (const float*)d_in[1];   // coords_std [16384,3] f32
    const int* ids  = (const int*)d_in[2];     // region_ids [16384] i32
    float* out = (float*)d_out;

    char* ws = (char*)d_ws;
    float4* pre = (float4*)ws;                                        // 256 KiB
    float* tauv = (float*)(ws + (size_t)B_N * 16);                    // 5.25 MiB
    unsigned short* cand =
        (unsigned short*)((char*)tauv + (size_t)NSUB * 5 * B_N * 4);  // 5.25 MiB
    float* tau = (float*)((char*)cand + (size_t)NCH * 5 * B_N * 2);   // 64 KiB
    float* wsreg = tau + B_N;                                         // 64 f
    float* spart = wsreg + NREG;                                      // 256 f
    int* counter = (int*)(spart + MRGBLK);                            // 1 int

    hipLaunchKernelGGL(prep_kernel, dim3(128), dim3(256), 0, stream, c, x, ids, pre, wsreg, counter);
    hipLaunchKernelGGL(tau_scan_kernel, dim3(64 * NSUB), dim3(256), 0, stream, pre, tauv);
    hipLaunchKernelGGL(tau_merge_kernel, dim3(64), dim3(256), 0, stream, tauv, tau);
    hipLaunchKernelGGL(spatial_kernel, dim3(64 * NCH), dim3(256), 0, stream, pre, tau, cand);
    hipLaunchKernelGGL(merge_kernel, dim3(MRGBLK), dim3(256), 0, stream, c, pre, cand, wsreg, spart, counter, out);
}

// Round 9
// 92.452 us; speedup vs baseline: 8.8658x; 1.1583x over previous
//
#include <hip/hip_runtime.h>
#include <stdint.h>

#define B_N    16384
#define NREG   64
#define KNB    5
#define SAMPLE 4096
#define NSUB   16
#define SUBLEN (SAMPLE / NSUB)       // 256 sample points per tau thread
#define NCH    32
#define CHLEN  (B_N / NCH)           // 512 scan points per spatial thread
#define MRGBLK 256                   // merge blocks (64 q each, 4 threads/q)
#define SENT   0xFFFF

static __device__ __forceinline__ float inf32() { return __int_as_float(0x7f800000); }
static __device__ __forceinline__ float med3(float a, float b, float c) {
    return __builtin_amdgcn_fmed3f(a, b, c);
}

// values-only sorted-insert into ascending s0..s4 (4 med3 + 1 min)
#define MINS5(nv)                      \
    {                                  \
        s4 = med3(s3, s4, (nv));       \
        s3 = med3(s2, s3, (nv));       \
        s2 = med3(s1, s2, (nv));       \
        s1 = med3(s0, s1, (nv));       \
        s0 = fminf(s0, (nv));          \
    }

// indexed flat 5-slot sorted-insert; strict < => ties keep earlier insert (smaller j)
#define INS5(nv, jj)                                                        \
    {                                                                       \
        bool c4 = (nv) < s4, c3 = (nv) < s3, c2 = (nv) < s2,                \
             c1 = (nv) < s1, c0 = (nv) < s0;                                \
        s4 = c3 ? s3 : (c4 ? (nv) : s4);  i4 = c3 ? i3 : (c4 ? (jj) : i4);  \
        s3 = c2 ? s2 : (c3 ? (nv) : s3);  i3 = c2 ? i2 : (c3 ? (jj) : i3);  \
        s2 = c1 ? s1 : (c2 ? (nv) : s2);  i2 = c1 ? i1 : (c2 ? (jj) : i2);  \
        s1 = c0 ? s0 : (c1 ? (nv) : s1);  i1 = c0 ? i0 : (c1 ? (jj) : i1);  \
        s0 = c0 ? (nv) : s0;              i0 = c0 ? (jj) : i0;              \
    }

// ---------------- K1: tau_scan (blocks 0..1023) + region/pre (blocks 1024..1087) ----------------
__global__ __launch_bounds__(256) void scan_region_kernel(const float* __restrict__ c,
                                                          const float* __restrict__ x,
                                                          const int* __restrict__ ids,
                                                          float4* __restrict__ pre,
                                                          float* __restrict__ tauv,
                                                          float* __restrict__ wsreg,
                                                          int* __restrict__ counter) {
    const int blk = blockIdx.x;
    const int tid = threadIdx.x;

    if (blk >= 1024) {
        // ---- region partials + pre[] writes (concurrent with tau_scan blocks) ----
        const int r = blk - 1024;
        if (r == 0 && tid == 0) *counter = 0;       // reset merge counter (used in K4)
        {
            int j = r * 256 + tid;
            float jx = x[3 * j + 0], jy = x[3 * j + 1], jz = x[3 * j + 2];
            pre[j] = make_float4(-2.f * jx, -2.f * jy, -2.f * jz,
                                 jx * jx + jy * jy + jz * jz);
        }
        float cnt = 0.f, sx = 0.f, sy = 0.f, sz = 0.f, sxx = 0.f, syy = 0.f, szz = 0.f;
        for (int i = tid; i < B_N; i += 256) {
            int id = ids[i];
            float m = (id == r) ? 1.0f : 0.0f;
            float px = c[3 * i + 0], py = c[3 * i + 1], pz = c[3 * i + 2];
            cnt += m;
            sx += m * px;  sy += m * py;  sz += m * pz;
            sxx += m * px * px;  syy += m * py * py;  szz += m * pz * pz;
        }
        for (int off = 32; off > 0; off >>= 1) {
            cnt += __shfl_down(cnt, off);
            sx  += __shfl_down(sx, off);
            sy  += __shfl_down(sy, off);
            sz  += __shfl_down(sz, off);
            sxx += __shfl_down(sxx, off);
            syy += __shfl_down(syy, off);
            szz += __shfl_down(szz, off);
        }
        __shared__ float sb[4][7];
        const int lane = tid & 63, w = tid >> 6;
        if (lane == 0) {
            sb[w][0] = cnt; sb[w][1] = sx; sb[w][2] = sy; sb[w][3] = sz;
            sb[w][4] = sxx; sb[w][5] = syy; sb[w][6] = szz;
        }
        __syncthreads();
        if (tid == 0) {
            float C = 0, SX = 0, SY = 0, SZ = 0, SXX = 0, SYY = 0, SZZ = 0;
            for (int i = 0; i < 4; i++) {
                C += sb[i][0]; SX += sb[i][1]; SY += sb[i][2]; SZ += sb[i][3];
                SXX += sb[i][4]; SYY += sb[i][5]; SZZ += sb[i][6];
            }
            float safe = fmaxf(C, 1.0f);
            float mx = SX / safe, my = SY / safe, mz = SZ / safe;
            float ssc = (SXX - C * mx * mx) + (SYY - C * my * my) + (SZZ - C * mz * mz);
            float npairs = C * (C - 1.0f) * 0.5f;
            float denom = fmaxf(npairs, 1.0f) * 3.0f;
            wsreg[r] = (C > 1.0f) ? (2.0f * ssc / denom) : 0.0f;
        }
        return;
    }

    // ---- tau_scan: LDS tile built inline from x ----
    __shared__ float4 tile[SUBLEN];           // 4 KiB
    const int qb = blk & 63;
    const int sub = blk >> 6;                 // 0..15
    const int q = qb * 256 + tid;
    const int j0 = sub * SUBLEN;
    {
        int j = j0 + tid;
        float jx = x[3 * j + 0], jy = x[3 * j + 1], jz = x[3 * j + 2];
        tile[tid] = make_float4(-2.f * jx, -2.f * jy, -2.f * jz,
                                jx * jx + jy * jy + jz * jz);
    }
    const float qx = x[3 * q + 0], qy = x[3 * q + 1], qz = x[3 * q + 2];
    __syncthreads();

    float s0 = inf32(), s1 = inf32(), s2 = inf32(), s3 = inf32(), s4 = inf32();

    for (int jb = 0; jb < SUBLEN; jb += 8) {
        float dt[8];
#pragma unroll
        for (int u = 0; u < 8; ++u) {
            float4 pj = tile[jb + u];         // wave-uniform -> LDS broadcast
            dt[u] = fmaf(pj.x, qx, fmaf(pj.y, qy, fmaf(pj.z, qz, pj.w)));
        }
#pragma unroll
        for (int u = 0; u < 8; ++u) {
            float nv = ((j0 + jb + u) != q) ? dt[u] : inf32();   // self-exclusion
            MINS5(nv);
        }
    }
    tauv[(sub * 5 + 0) * B_N + q] = s0;       // transposed: coalesced in q
    tauv[(sub * 5 + 1) * B_N + q] = s1;
    tauv[(sub * 5 + 2) * B_N + q] = s2;
    tauv[(sub * 5 + 3) * B_N + q] = s3;
    tauv[(sub * 5 + 4) * B_N + q] = s4;
}

// ---------------- K2: merge 80 sample values -> bumped tau[q] (once per q) ----------------
__global__ __launch_bounds__(256) void tau_merge_kernel(const float* __restrict__ tauv,
                                                        float* __restrict__ tau) {
    const int q = blockIdx.x * 256 + threadIdx.x;
    float s0 = inf32(), s1 = inf32(), s2 = inf32(), s3 = inf32(), s4 = inf32();
#pragma unroll 8
    for (int n = 0; n < NSUB * 5; ++n) {
        float v = tauv[n * B_N + q];          // coalesced
        MINS5(v);
    }
    int b = __float_as_int(s4);               // bump 1 ulp: admit d == tau ties
    b += (b >= 0) ? 1 : -1;
    tau[q] = __int_as_float(b);
}

// ---------------- K3: tau-filtered scan of an LDS-staged 512-chunk ----------------
__global__ __launch_bounds__(256) void spatial_kernel(const float4* __restrict__ pre,
                                                      const float* __restrict__ tau,
                                                      unsigned short* __restrict__ cand) {
    __shared__ float4 tile[CHLEN];            // 8 KiB
    const int tid = threadIdx.x;
    const int qb = blockIdx.x & 63;
    const int ch = blockIdx.x >> 6;           // 0..31
    const int q = qb * 256 + tid;
    const int jbase = ch * CHLEN;

#pragma unroll
    for (int i = 0; i < CHLEN / 256; ++i)     // coalesced tile load
        tile[tid + i * 256] = pre[jbase + tid + i * 256];

    const float4 pq = pre[q];
    const float qx = -0.5f * pq.x, qy = -0.5f * pq.y, qz = -0.5f * pq.z;
    const float t = tau[q];
    __syncthreads();

    float s0 = t, s1 = t, s2 = t, s3 = t, s4 = t;
    int i0 = SENT, i1 = SENT, i2 = SENT, i3 = SENT, i4 = SENT;

    for (int jb = 0; jb < CHLEN; jb += 8) {
        float dt[8];
#pragma unroll
        for (int u = 0; u < 8; ++u) {
            float4 pj = tile[jb + u];         // wave-uniform -> LDS broadcast
            dt[u] = fmaf(pj.x, qx, fmaf(pj.y, qy, fmaf(pj.z, qz, pj.w)));
        }
        // group-of-8 min prefilter: ONE ballot/branch per 8 points (fmin tree -> v_min3)
        float m = fminf(fminf(fminf(dt[0], dt[1]), fminf(dt[2], dt[3])),
                        fminf(fminf(dt[4], dt[5]), fminf(dt[6], dt[7])));
        if (__builtin_expect(__any(m < s4), 0)) {
#pragma unroll
            for (int u = 0; u < 8; ++u) {
                if (__any(dt[u] < s4)) {      // exact per-u path, order preserved
                    int j = jbase + jb + u;
                    bool p = (dt[u] < s4) && (j != q);
                    float nv = p ? dt[u] : inf32();
                    INS5(nv, j);
                }
            }
        }
    }
    cand[(ch * 5 + 0) * B_N + q] = (unsigned short)i0;   // transposed: coalesced
    cand[(ch * 5 + 1) * B_N + q] = (unsigned short)i1;
    cand[(ch * 5 + 2) * B_N + q] = (unsigned short)i2;
    cand[(ch * 5 + 3) * B_N + q] = (unsigned short)i3;
    cand[(ch * 5 + 4) * B_N + q] = (unsigned short)i4;
}

// ---------------- K4: final merge (4 threads/q) + c-loss + last-block finalize ----------------
__global__ __launch_bounds__(256) void merge_kernel(const float* __restrict__ c,
                                                    const float4* __restrict__ pre,
                                                    const unsigned short* __restrict__ cand,
                                                    const float* __restrict__ wsreg,
                                                    float* __restrict__ spart,
                                                    int* __restrict__ counter,
                                                    float* __restrict__ out) {
    const int tid = threadIdx.x;
    const int blk = blockIdx.x;
    const int qloc = tid >> 2;                // 0..63
    const int part = tid & 3;                 // 0..3 (chunks part*8 .. part*8+7)
    const int q = blk * 64 + qloc;
    const float4 pq = pre[q];
    const float qx = -0.5f * pq.x, qy = -0.5f * pq.y, qz = -0.5f * pq.z;

    __shared__ float dm[64][4][5];
    __shared__ unsigned short im[64][4][5];

    {
        float s0 = inf32(), s1 = inf32(), s2 = inf32(), s3 = inf32(), s4 = inf32();
        int i0 = SENT & 0x3FFF, i1 = i0, i2 = i0, i3 = i0, i4 = i0;
        const int n0 = part * (NCH / 4) * 5;  // 40 slots, chunk-ascending
#pragma unroll 8
        for (int n = n0; n < n0 + (NCH / 4) * 5; ++n) {
            int cd = (int)cand[n * B_N + q];
            int safe = cd & 0x3FFF;           // SENT -> valid addr, masked below
            float4 pj = pre[safe];
            float d = fmaf(pj.x, qx, fmaf(pj.y, qy, fmaf(pj.z, qz, pj.w)));
            float nv = (cd != SENT) ? d : inf32();
            INS5(nv, safe);
        }
        dm[qloc][part][0] = s0; im[qloc][part][0] = (unsigned short)i0;
        dm[qloc][part][1] = s1; im[qloc][part][1] = (unsigned short)i1;
        dm[qloc][part][2] = s2; im[qloc][part][2] = (unsigned short)i2;
        dm[qloc][part][3] = s3; im[qloc][part][3] = (unsigned short)i3;
        dm[qloc][part][4] = s4; im[qloc][part][4] = (unsigned short)i4;
    }
    __syncthreads();

    float acc = 0.f;
    if (part == 0) {
        float s0 = inf32(), s1 = inf32(), s2 = inf32(), s3 = inf32(), s4 = inf32();
        int i0 = 0, i1 = 0, i2 = 0, i3 = 0, i4 = 0;
#pragma unroll
        for (int p = 0; p < 4; ++p)           // ascending p = ascending chunks
#pragma unroll
            for (int k = 0; k < 5; ++k) {
                float nv = dm[qloc][p][k];
                int jj = (int)im[qloc][p][k];
                INS5(nv, jj);
            }
        const float cx = c[3 * q + 0], cy = c[3 * q + 1], cz = c[3 * q + 2];
        int ks[5] = {i0, i1, i2, i3, i4};
#pragma unroll
        for (int n = 0; n < KNB; ++n) {
            int nb = ks[n];
            float dx = cx - c[3 * nb + 0];
            float dy = cy - c[3 * nb + 1];
            float dz = cz - c[3 * nb + 2];
            acc += dx * dx + dy * dy + dz * dz;
        }
    }
    // acc nonzero on lanes == 0 mod 4; offsets 32,16,8,4 sum them onto lane 0
    acc += __shfl_down(acc, 32);
    acc += __shfl_down(acc, 16);
    acc += __shfl_down(acc, 8);
    acc += __shfl_down(acc, 4);
    __shared__ float wsum[4];
    __shared__ int last;
    const int lane = tid & 63, w = tid >> 6;
    if (lane == 0) wsum[w] = acc;
    __syncthreads();
    if (tid == 0) {
        float bs = wsum[0] + wsum[1] + wsum[2] + wsum[3];
        atomicExch(&spart[blk], bs);          // device-scope visible store
        __threadfence();
        int old = atomicAdd(counter, 1);
        last = (old == MRGBLK - 1);
    }
    __syncthreads();
    if (last) {
        // fixed-order reduction => bitwise deterministic regardless of which block runs it
        float s = atomicAdd(&spart[tid], 0.0f);          // device-scope read, 256 partials
        float r = (tid < NREG) ? wsreg[tid] : 0.f;
        for (int off = 32; off > 0; off >>= 1) {
            s += __shfl_down(s, off);
            r += __shfl_down(r, off);
        }
        __shared__ float fb[4];
        if (lane == 0) fb[w] = s;
        __syncthreads();
        if (tid == 0) {
            float S = fb[0] + fb[1] + fb[2] + fb[3];
            float spatial_mean = S / (float)(B_N * KNB);
            out[0] = 0.02f * r + 0.0005f * (spatial_mean / 3.0f);
        }
    }
}

extern "C" void kernel_launch(void* const* d_in, const int* in_sizes, int n_in,
                              void* d_out, int out_size, void* d_ws, size_t ws_size,
                              hipStream_t stream) {
    const float* c  = (const float*)d_in[0];   // c_points   [16384,3] f32
    const float* x  = (const float*)d_in[1];   // coords_std [16384,3] f32
    const int* ids  = (const int*)d_in[2];     // region_ids [16384] i32
    float* out = (float*)d_out;

    char* ws = (char*)d_ws;
    float4* pre = (float4*)ws;                                        // 256 KiB
    float* tauv = (float*)(ws + (size_t)B_N * 16);                    // 5.25 MiB
    unsigned short* cand =
        (unsigned short*)((char*)tauv + (size_t)NSUB * 5 * B_N * 4);  // 5.25 MiB
    float* tau = (float*)((char*)cand + (size_t)NCH * 5 * B_N * 2);   // 64 KiB
    float* wsreg = tau + B_N;                                         // 64 f
    float* spart = wsreg + NREG;                                      // 256 f
    int* counter = (int*)(spart + MRGBLK);                            // 1 int

    hipLaunchKernelGGL(scan_region_kernel, dim3(1088), dim3(256), 0, stream,
                       c, x, ids, pre, tauv, wsreg, counter);
    hipLaunchKernelGGL(tau_merge_kernel, dim3(64), dim3(256), 0, stream, tauv, tau);
    hipLaunchKernelGGL(spatial_kernel, dim3(64 * NCH), dim3(256), 0, stream, pre, tau, cand);
    hipLaunchKernelGGL(merge_kernel, dim3(MRGBLK), dim3(256), 0, stream, c, pre, cand,
                       wsreg, spart, counter, out);
}